// Round 5
// baseline (402.925 us; speedup 1.0000x reference)
//
#include <hip/hip_runtime.h>
#include <hip/hip_bf16.h>
#include <stdint.h>

typedef unsigned short u16;
typedef unsigned int   u32;
typedef __attribute__((ext_vector_type(8)))  __bf16 bf16x8;
typedef __attribute__((ext_vector_type(4)))  int    i32x4;
typedef __attribute__((ext_vector_type(4)))  float  f32x4;

#define DEV __device__ __forceinline__

#define N_USERS 4096
#define MX      500
#define MG      50
#define KR8     2560   // rating K (2500 pad to 128)
#define KG16    1024   // genre K (1000 pad to 64)
#define RN      1536

// ---- workspace layout (bytes) ----
#define OFF_A8  ((size_t)0)                       // i8  [4096][2560]
#define OFF_B8  ((size_t)10485760)                // i8  [4096][2560]
#define OFF_A16 ((size_t)20971520)                // bf16[4096][1024]
#define OFF_B16 ((size_t)29360128)                // bf16[4096][1024]
#define OFF_P   ((size_t)0)                       // bf16 P [4096][4096]
#define OFF_R   ((size_t)37748736)                // bf16 RHST [1536][4096]
#define OFF_S   ((size_t)58720256)                // f32 sims [4096][4096]
#define OFF_O   ((size_t)58720256)                // f32 O parts
#define OFF_SC  ((size_t)138412032)               // f32 scalars[8]
#define OFF_WX8 (OFF_SC + 2048)
#define OFF_WGB (OFF_SC + 2112)
#define OFF_MR  (OFF_SC + 4096)
#define OFF_MC  (OFF_SC + 4096 + 16384)
#define WS_REQUIRED (OFF_MC + 4096)
#define O_PART  ((size_t)4096 * RN)

DEV u16 f2bf(float f) {
  union { float f; u32 u; } v; v.f = f;
  u32 r = v.u + 0x7FFFu + ((v.u >> 16) & 1u);
  return (u16)(r >> 16);
}
DEV float bf2f(u16 u) {
  union { u32 u; float f; } v; v.u = ((u32)u) << 16;
  return v.f;
}

DEV void glds16(const void* g, void* l) {
  __builtin_amdgcn_global_load_lds(
      (const __attribute__((address_space(1))) void*)g,
      (__attribute__((address_space(3))) void*)l, 16, 0, 0);
}

// ---------------- prep ----------------
__global__ __launch_bounds__(256) void k_prep(const void* wx, const void* wg,
                                              const void* beta, const void* gamma,
                                              const void* coef, float* sc,
                                              char* wx8, u16* wgb) {
  __shared__ int sflag;
  int t = threadIdx.x;
  if (t == 0) {
    u32 u = ((const u32*)wx)[5];
    int f = (u == 0x40400000u) ? 1 : 0;
    sflag = f;
    ((int*)sc)[0] = f;
  }
  __syncthreads();
  int f = sflag;
  auto rd = [&](const void* p, int i) -> float {
    return f ? ((const float*)p)[i] : bf2f(((const u16*)p)[i]);
  };
  if (t == 0) {
    sc[1] = rd(beta, 0); sc[2] = rd(gamma, 0);
    sc[3] = rd(coef, 0); sc[4] = rd(coef, 1); sc[5] = rd(coef, 2);
  }
  for (int i = t; i < 30;  i += 256) wx8[i] = (char)__float2int_rn(rd(wx, i));
  for (int i = t; i < 420; i += 256) wgb[i] = f2bf(rd(wg, i));
}

// ---------------- means ----------------
__global__ __launch_bounds__(64) void k_means_rows(const int* __restrict__ x, float* __restrict__ mr) {
  int i = blockIdx.x, t = threadIdx.x;
  const int* row = x + (size_t)i * MX;
  float s = 0.f, c = 0.f;
  for (int m = t; m < MX; m += 64) { int a = row[m]; s += (float)a; c += (a > 0) ? 1.f : 0.f; }
  for (int off = 32; off >= 1; off >>= 1) { s += __shfl_xor(s, off); c += __shfl_xor(c, off); }
  if (t == 0) mr[i] = s / (c + 1e-5f);
}

__global__ __launch_bounds__(256) void k_means_cols(const int* __restrict__ x, float* __restrict__ mc) {
  int m = blockIdx.x, t = threadIdx.x;
  float s = 0.f, c = 0.f;
  for (int i = t; i < N_USERS; i += 256) { int a = x[(size_t)i * MX + m]; s += (float)a; c += (a > 0) ? 1.f : 0.f; }
  __shared__ float ss[4], cs[4];
  for (int off = 32; off >= 1; off >>= 1) { s += __shfl_xor(s, off); c += __shfl_xor(c, off); }
  int w = t >> 6, lane = t & 63;
  if (lane == 0) { ss[w] = s; cs[w] = c; }
  __syncthreads();
  if (t == 0) {
    s = ss[0] + ss[1] + ss[2] + ss[3];
    c = cs[0] + cs[1] + cs[2] + cs[3];
    mc[m] = s / (c + 1e-5f);
  }
}

__global__ __launch_bounds__(256) void k_scalars(const float* __restrict__ mr, const float* __restrict__ mc, float* sc) {
  int t = threadIdx.x;
  float s1 = 0.f, s2 = 0.f;
  for (int i = t; i < N_USERS; i += 256) s1 += mr[i];
  for (int i = t; i < MX; i += 256) s2 += mc[i];
  __shared__ float a1[4], a2[4];
  for (int off = 32; off >= 1; off >>= 1) { s1 += __shfl_xor(s1, off); s2 += __shfl_xor(s2, off); }
  int w = t >> 6, lane = t & 63;
  if (lane == 0) { a1[w] = s1; a2[w] = s2; }
  __syncthreads();
  if (t == 0) {
    sc[6] = (a1[0] + a1[1] + a1[2] + a1[3]) / (float)N_USERS;
    sc[7] = (a2[0] + a2[1] + a2[2] + a2[3]) / (float)MX;
  }
}

// ---------------- build operands ----------------
__global__ __launch_bounds__(256) void k_buildAB(const int* __restrict__ xi, const int* __restrict__ gi,
                                                 const char* __restrict__ wx8, const u16* __restrict__ wgb,
                                                 char* __restrict__ A8, char* __restrict__ B8,
                                                 u16* __restrict__ A16, u16* __restrict__ B16) {
  int i = blockIdx.x, t = threadIdx.x;
  char* a8 = A8 + (size_t)i * KR8;
  char* b8 = B8 + (size_t)i * KR8;
  u16* a16 = A16 + (size_t)i * KG16;
  u16* b16 = B16 + (size_t)i * KG16;
  const int* xr = xi + (size_t)i * MX;
  const int* gr = gi + (size_t)i * MG;
  for (int m = t; m < MX; m += 256) {
    int a = xr[m];
    int base = m * 5;
#pragma unroll
    for (int d = 0; d < 5; ++d) {
      a8[base + d] = wx8[a * 5 + d];
      b8[base + d] = (a == d + 1) ? (char)1 : (char)0;
    }
  }
  for (int e = 2500 + t; e < KR8; e += 256) { a8[e] = 0; b8[e] = 0; }
  for (int m = t; m < MG; m += 256) {
    int g = gr[m];
    int base = m * 20;
#pragma unroll
    for (int d = 0; d < 20; ++d) {
      a16[base + d] = wgb[g * 20 + d];
      b16[base + d] = (g == d + 1) ? (u16)0x3F80 : (u16)0;
    }
  }
  for (int e = 1000 + t; e < KG16; e += 256) { a16[e] = 0; b16[e] = 0; }
}

// ---------------- m201-style 8-phase 256x256 GEMM, mixed i8 + bf16 ----------------
// K-tile = 128B row-chunk ([128][128B] half-tiles, st_16x32 swizzle).
// 2 dbuf slots x {A 2 halves, B 2 halves} x 16KB = 128 KiB LDS.
// Per iteration (2 K-tiles): 8 phases; stage table: p0,p1->A(t+1); p2,p3->B(t+2);
// p4,p5->A(t+2); p6,p7->B(t+3). vmcnt(4) at p3 and p7 only (0 in final iter).
__global__ __launch_bounds__(512, 2) void k_gemm8p(
    const char* __restrict__ A8g, const char* __restrict__ B8g,
    const char* __restrict__ A16g, const char* __restrict__ B16g,
    float* __restrict__ Cg, int N, int nt1, int ntT,
    int ld8, int ld16, int kz16, unsigned long long czStride)
{
  extern __shared__ __align__(16) char ldsc[];
  const int t = threadIdx.x, l = t & 63, w = t >> 6;
  const int wm = w >> 2, wn = w & 3;   // 2M x 4N waves; wave tile 128x64

  int nwg = gridDim.x * gridDim.y;
  int o = blockIdx.y * gridDim.x + blockIdx.x;
  int swzb = (o & 7) * (nwg >> 3) + (o >> 3);
  int bn = swzb % gridDim.x, bm = swzb / gridDim.x;

  const char* pA8  = A8g  + (size_t)bm * 256 * ld8;
  const char* pB8  = B8g  + (size_t)bn * 256 * ld8;
  const char* pA16 = A16g + (size_t)bm * 256 * ld16 + (size_t)blockIdx.z * kz16;
  const char* pB16 = B16g + (size_t)bn * 256 * ld16 + (size_t)blockIdx.z * kz16;
  float* C = Cg + (size_t)blockIdx.z * czStride;

  // per-lane swizzled read offsets (st_16x32: byte ^= ((row>>2)&1)<<5)
  const int sb = ((l & 15) >> 2) & 1;
  const int kpart = ((l >> 4) * 16) ^ (sb << 5);
  const int ofsA = (l & 15) * 128 + kpart;
  const int ofsB = ((wn & 1) * 64 + (l & 15)) * 128 + kpart;

  // staging: pre-swizzled global source, linear LDS dest (lane*16)
  const int swslot = ((l & 7) ^ (((l >> 5) & 1) << 1)) * 16;
  int vof8[2], vof16[2];
#pragma unroll
  for (int c = 0; c < 2; ++c) {
    int rl = w * 16 + c * 8 + (l >> 3);
    vof8[c]  = rl * ld8  + swslot;
    vof16[c] = rl * ld16 + swslot;
  }

  auto stageU = [&](int tt, int which) {  // which: 0=Ah0 1=Ah1 2=Bh0 3=Bh1
    if (tt >= ntT) return;
    const int h = which & 1;
    const bool isB = which >= 2;
    char* dst = ldsc + ((tt & 1) << 16) + (isB ? 32768 : 0) + (h << 14) + w * 2048;
    if (tt < nt1) {
      const char* bp = (isB ? pB8 : pA8) + ((size_t)tt << 7) + (h ? ((size_t)ld8 << 7) : (size_t)0);
      glds16(bp + vof8[0], dst);
      glds16(bp + vof8[1], dst + 1024);
    } else {
      const char* bp = (isB ? pB16 : pA16) + ((size_t)(tt - nt1) << 7) + (h ? ((size_t)ld16 << 7) : (size_t)0);
      glds16(bp + vof16[0], dst);
      glds16(bp + vof16[1], dst + 1024);
    }
  };

  i32x4 acc[8][4] = {};
  f32x4 (&accF)[8][4] = reinterpret_cast<f32x4(&)[8][4]>(acc);

  const char* Abase = ldsc + (wm << 14) + ofsA;
  const char* Bbase = ldsc + 32768 + ((wn >> 1) << 14) + ofsB;

  // prologue: mimic steady-state prev-iteration stages for tiles 0,1
  stageU(0, 2); stageU(0, 3); stageU(0, 0); stageU(0, 1); stageU(1, 2); stageU(1, 3);
  asm volatile("s_waitcnt vmcnt(4)" ::: "memory");
  __builtin_amdgcn_s_barrier();
  __builtin_amdgcn_sched_barrier(0);

  const int nIter = ntT >> 1;
  int it = 0;

#define PH_BAR_MFMA(MFMA, VT, ACC, AIDX, BIDX0)                               \
    __builtin_amdgcn_s_barrier();                                             \
    asm volatile("s_waitcnt lgkmcnt(0)" ::: "memory");                        \
    __builtin_amdgcn_sched_barrier(0);                                        \
    __builtin_amdgcn_s_setprio(1);                                            \
    _Pragma("unroll") for (int j = 0; j < 4; ++j)                             \
      _Pragma("unroll") for (int n = 0; n < 2; ++n)                           \
        _Pragma("unroll") for (int k = 0; k < 2; ++k)                         \
          ACC[AIDX + j][BIDX0 + n] =                                          \
              MFMA(a[j][k], b[BIDX0 + n][k], ACC[AIDX + j][BIDX0 + n], 0, 0, 0); \
    __builtin_amdgcn_s_setprio(0);

#define GEMM_ITER(MFMA, VT, ACC)                                              \
  {                                                                           \
    const int tb = it << 1;                                                   \
    VT a[4][2], b[4][2];                                                      \
    const char* A0 = Abase;                                                   \
    const char* B0 = Bbase;                                                   \
    const char* A1 = Abase + 65536;                                           \
    const char* B1 = Bbase + 65536;                                           \
    /* p0: Q0(tb) */                                                          \
    _Pragma("unroll") for (int j = 0; j < 4; ++j)                             \
      _Pragma("unroll") for (int k = 0; k < 2; ++k)                           \
        a[j][k] = *(const VT*)(A0 + j * 2048 + k * 64);                       \
    _Pragma("unroll") for (int n = 0; n < 2; ++n)                             \
      _Pragma("unroll") for (int k = 0; k < 2; ++k)                           \
        b[n][k] = *(const VT*)(B0 + n * 2048 + k * 64);                       \
    stageU(tb + 1, 0);                                                        \
    asm volatile("s_waitcnt lgkmcnt(8)" ::: "memory");                        \
    PH_BAR_MFMA(MFMA, VT, ACC, 0, 0)                                         \
    __builtin_amdgcn_s_barrier();                                             \
    /* p1: Q1(tb) */                                                          \
    _Pragma("unroll") for (int n = 0; n < 2; ++n)                             \
      _Pragma("unroll") for (int k = 0; k < 2; ++k)                           \
        b[2 + n][k] = *(const VT*)(B0 + (2 + n) * 2048 + k * 64);             \
    stageU(tb + 1, 1);                                                        \
    PH_BAR_MFMA(MFMA, VT, ACC, 0, 2)                                         \
    __builtin_amdgcn_s_barrier();                                             \
    /* p2: Q2(tb) */                                                          \
    _Pragma("unroll") for (int j = 0; j < 4; ++j)                             \
      _Pragma("unroll") for (int k = 0; k < 2; ++k)                           \
        a[j][k] = *(const VT*)(A0 + (4 + j) * 2048 + k * 64);                 \
    stageU(tb + 2, 2);                                                        \
    asm volatile("s_waitcnt lgkmcnt(4)" ::: "memory");                        \
    PH_BAR_MFMA(MFMA, VT, ACC, 4, 0)                                         \
    __builtin_amdgcn_s_barrier();                                             \
    /* p3: Q3(tb) */                                                          \
    stageU(tb + 2, 3);                                                        \
    if (it == nIter - 1) asm volatile("s_waitcnt vmcnt(0)" ::: "memory");     \
    else                 asm volatile("s_waitcnt vmcnt(4)" ::: "memory");     \
    PH_BAR_MFMA(MFMA, VT, ACC, 4, 2)                                         \
    __builtin_amdgcn_s_barrier();                                             \
    /* p4: Q0(tb+1) */                                                        \
    _Pragma("unroll") for (int j = 0; j < 4; ++j)                             \
      _Pragma("unroll") for (int k = 0; k < 2; ++k)                           \
        a[j][k] = *(const VT*)(A1 + j * 2048 + k * 64);                       \
    _Pragma("unroll") for (int n = 0; n < 2; ++n)                             \
      _Pragma("unroll") for (int k = 0; k < 2; ++k)                           \
        b[n][k] = *(const VT*)(B1 + n * 2048 + k * 64);                       \
    stageU(tb + 2, 0);                                                        \
    asm volatile("s_waitcnt lgkmcnt(8)" ::: "memory");                        \
    PH_BAR_MFMA(MFMA, VT, ACC, 0, 0)                                         \
    __builtin_amdgcn_s_barrier();                                             \
    /* p5: Q1(tb+1) */                                                        \
    _Pragma("unroll") for (int n = 0; n < 2; ++n)                             \
      _Pragma("unroll") for (int k = 0; k < 2; ++k)                           \
        b[2 + n][k] = *(const VT*)(B1 + (2 + n) * 2048 + k * 64);             \
    stageU(tb + 2, 1);                                                        \
    PH_BAR_MFMA(MFMA, VT, ACC, 0, 2)                                         \
    __builtin_amdgcn_s_barrier();                                             \
    /* p6: Q2(tb+1) */                                                        \
    _Pragma("unroll") for (int j = 0; j < 4; ++j)                             \
      _Pragma("unroll") for (int k = 0; k < 2; ++k)                           \
        a[j][k] = *(const VT*)(A1 + (4 + j) * 2048 + k * 64);                 \
    stageU(tb + 3, 2);                                                        \
    asm volatile("s_waitcnt lgkmcnt(4)" ::: "memory");                        \
    PH_BAR_MFMA(MFMA, VT, ACC, 4, 0)                                         \
    __builtin_amdgcn_s_barrier();                                             \
    /* p7: Q3(tb+1) */                                                        \
    stageU(tb + 3, 3);                                                        \
    PH_BAR_MFMA(MFMA, VT, ACC, 4, 2)                                         \
    if (it != nIter - 1) asm volatile("s_waitcnt vmcnt(4)" ::: "memory");     \
    __builtin_amdgcn_s_barrier();                                             \
  }

  // ---- loop 1: i8 (exact i32 accumulate) ----
  for (; it < (nt1 >> 1); ++it)
    GEMM_ITER(__builtin_amdgcn_mfma_i32_16x16x64_i8, i32x4, acc)

  // convert i32 -> f32 in place
#pragma unroll
  for (int m = 0; m < 8; ++m)
#pragma unroll
    for (int n = 0; n < 4; ++n)
#pragma unroll
      for (int e = 0; e < 4; ++e) {
        int v = acc[m][n][e];
        accF[m][n][e] = (float)v;
      }

  // ---- loop 2: bf16 ----
  for (; it < nIter; ++it)
    GEMM_ITER(__builtin_amdgcn_mfma_f32_16x16x32_bf16, bf16x8, accF)

#undef GEMM_ITER
#undef PH_BAR_MFMA

  // C write: 16x16 C/D layout: col = lane&15, row = (lane>>4)*4 + r
  const int colb = bn * 256 + wn * 64 + (l & 15);
  const int rowb = bm * 256 + wm * 128 + ((l >> 4) << 2);
#pragma unroll
  for (int m = 0; m < 8; ++m)
#pragma unroll
    for (int n = 0; n < 4; ++n) {
      float* Cp = C + (size_t)(rowb + m * 16) * N + colb + n * 16;
#pragma unroll
      for (int r = 0; r < 4; ++r)
        Cp[(size_t)r * N] = accF[m][n][r];
    }
}

// ---------------- softmax ----------------
__global__ __launch_bounds__(256) void k_softmax(const float* __restrict__ S, u16* __restrict__ P,
                                                 const float* __restrict__ sc) {
  int i = blockIdx.x, t = threadIdx.x;
  const float* row = S + (size_t)i * N_USERS;
  float v[16];
#pragma unroll
  for (int c = 0; c < 4; ++c) {
    float4 f = *(const float4*)&row[(c * 256 + t) * 4];
    v[c * 4 + 0] = f.x; v[c * 4 + 1] = f.y; v[c * 4 + 2] = f.z; v[c * 4 + 3] = f.w;
  }
#pragma unroll
  for (int c = 0; c < 4; ++c) {
    int j0 = (c * 256 + t) * 4;
#pragma unroll
    for (int q = 0; q < 4; ++q) if (j0 + q == i) v[c * 4 + q] = 0.f;
  }
  float mx = -1e30f;
#pragma unroll
  for (int e = 0; e < 16; ++e) mx = fmaxf(mx, v[e]);
  __shared__ float red[8];
  for (int off = 32; off >= 1; off >>= 1) mx = fmaxf(mx, __shfl_xor(mx, off));
  int w = t >> 6, lane = t & 63;
  if (lane == 0) red[w] = mx;
  __syncthreads();
  mx = fmaxf(fmaxf(red[0], red[1]), fmaxf(red[2], red[3]));

  float invT = 1.f / (powf(mx + 0.001f, sc[2]) * sc[1]);
  float s = 0.f;
#pragma unroll
  for (int e = 0; e < 16; ++e) { v[e] = expf((v[e] - mx) * invT); s += v[e]; }
  for (int off = 32; off >= 1; off >>= 1) s += __shfl_xor(s, off);
  if (lane == 0) red[4 + w] = s;
  __syncthreads();
  s = red[4] + red[5] + red[6] + red[7];
  float rs = 1.f / s;

  u16* prow = P + (size_t)i * N_USERS;
#pragma unroll
  for (int c = 0; c < 4; ++c) {
    int j0 = (c * 256 + t) * 4;
    union { u16 q[4]; uint2 u; } pk;
#pragma unroll
    for (int q = 0; q < 4; ++q) pk.q[q] = f2bf(v[c * 4 + q] * rs);
    *(uint2*)&prow[j0] = pk.u;
  }
}

// ---------------- build RHS^T ----------------
__global__ __launch_bounds__(256) void k_buildR(const int* __restrict__ xi, const float* __restrict__ mr,
                                                u16* __restrict__ R) {
  int k = blockIdx.x * 256 + threadIdx.x;
  int n = blockIdx.y;
  u16 v;
  if (n < 500)       { int a = xi[(size_t)k * MX + n];          v = f2bf((float)a); }
  else if (n < 1000) { int a = xi[(size_t)k * MX + (n - 500)];  v = (a > 0) ? (u16)0x3F80 : (u16)0; }
  else if (n < 1500) { int a = xi[(size_t)k * MX + (n - 1000)]; v = (a > 0) ? f2bf(mr[k]) : (u16)0; }
  else v = 0;
  R[(size_t)n * N_USERS + k] = v;
}

// ---------------- final ----------------
__global__ __launch_bounds__(256) void k_final(const float* __restrict__ O, const float* __restrict__ mr,
                                               const float* __restrict__ mc, const float* __restrict__ sc,
                                               void* __restrict__ out) {
  int m = blockIdx.x * 256 + threadIdx.x;
  int i = blockIdx.y;
  if (m >= MX) return;
  const float* o0 = O + (size_t)i * RN;
  const float* o1 = o0 + O_PART;
  float mult  = o0[m] + o1[m];
  float scale = o0[500 + m] + o1[500 + m] + 1e-4f;
  float mrs   = (o0[1000 + m] + o1[1000 + m]) / scale;
  float res   = mult / scale;
  float c0 = sc[3], c1 = sc[4], c2 = sc[5], mrm = sc[6], mcm = sc[7];
  float add = (mr[i] - mrs) * c0 + (mc[m] - mcm) * c1 + (mr[i] - mrm) * c2;
  float r = res + add;
  r = fminf(fmaxf(r, 1.f), 5.f);
  int f32mode = ((const int*)sc)[0];
  if (f32mode) ((float*)out)[(size_t)i * MX + m] = r;
  else         ((u16*)out)[(size_t)i * MX + m] = f2bf(r);
}

extern "C" void kernel_launch(void* const* d_in, const int* in_sizes, int n_in,
                              void* d_out, int out_size, void* d_ws, size_t ws_size,
                              hipStream_t stream) {
  if (ws_size < WS_REQUIRED) return;
  const int* xi = (const int*)d_in[0];
  const int* gi = (const int*)d_in[1];
  char* ws = (char*)d_ws;
  char*  A8  = ws + OFF_A8;
  char*  B8  = ws + OFF_B8;
  u16*   A16 = (u16*)(ws + OFF_A16);
  u16*   B16 = (u16*)(ws + OFF_B16);
  u16*   P   = (u16*)(ws + OFF_P);
  float* S   = (float*)(ws + OFF_S);
  float* O   = (float*)(ws + OFF_O);
  u16*   R   = (u16*)(ws + OFF_R);
  float* sc  = (float*)(ws + OFF_SC);
  char*  wx8 = ws + OFF_WX8;
  u16*   wgb = (u16*)(ws + OFF_WGB);
  float* mr  = (float*)(ws + OFF_MR);
  float* mc  = (float*)(ws + OFF_MC);

  (void)hipFuncSetAttribute((const void*)k_gemm8p,
                            hipFuncAttributeMaxDynamicSharedMemorySize, 131072);

  k_prep<<<1, 256, 0, stream>>>(d_in[2], d_in[4], d_in[6], d_in[7], d_in[8], sc, wx8, wgb);
  k_means_rows<<<N_USERS, 64, 0, stream>>>(xi, mr);
  k_means_cols<<<MX, 256, 0, stream>>>(xi, mc);
  k_scalars<<<1, 256, 0, stream>>>(mr, mc, sc);
  k_buildAB<<<N_USERS, 256, 0, stream>>>(xi, gi, wx8, wgb, A8, B8, A16, B16);
  // GEMM1: sims = A8*B8^T (i8, 20 K-tiles) + A16*B16^T (bf16, 16 K-tiles)
  k_gemm8p<<<dim3(16, 16, 1), 512, 131072, stream>>>(
      A8, B8, (const char*)A16, (const char*)B16, S, N_USERS,
      20, 36, KR8, KG16 * 2, 0, 0ull);
  k_softmax<<<N_USERS, 256, 0, stream>>>(S, P, sc);
  k_buildR<<<dim3(16, RN), 256, 0, stream>>>(xi, mr, R);
  // GEMM2: O = P * R^T, bf16 only, split-K=2 (32 K-tiles per z)
  k_gemm8p<<<dim3(RN / 256, 16, 2), 512, 131072, stream>>>(
      (const char*)P, (const char*)R, (const char*)P, (const char*)R, O, RN,
      0, 32, N_USERS * 2, N_USERS * 2, N_USERS, (unsigned long long)O_PART);
  k_final<<<dim3(2, N_USERS), 256, 0, stream>>>(O, mr, mc, sc, d_out);
}

// Round 6
// 232.207 us; speedup vs baseline: 1.7352x; 1.7352x over previous
//
#include <hip/hip_runtime.h>
#include <hip/hip_bf16.h>
#include <stdint.h>

typedef unsigned short u16;
typedef unsigned int   u32;
typedef __attribute__((ext_vector_type(8)))  __bf16 bf16x8;
typedef __attribute__((ext_vector_type(4)))  int    i32x4;
typedef __attribute__((ext_vector_type(16))) int    i32x16;
typedef __attribute__((ext_vector_type(16))) float  f32x16;

#define DEV __device__ __forceinline__

#define N_USERS 4096
#define MX      500
#define MG      50
#define KR8     2560   // rating K (2500 pad to 64)
#define KG16    1024   // genre K (1000 pad to 32)
#define RN      1536

// ---- workspace layout (bytes) ----
#define OFF_A8  ((size_t)0)                       // i8  [4096][2560]
#define OFF_B8  ((size_t)10485760)                // i8  [4096][2560]
#define OFF_A16 ((size_t)20971520)                // bf16[4096][1024]
#define OFF_B16 ((size_t)29360128)                // bf16[4096][1024]
#define OFF_P   ((size_t)0)                       // bf16 P [4096][4096]
#define OFF_R   ((size_t)37748736)                // bf16 RHST [1536][4096]
#define OFF_S   ((size_t)58720256)                // f32 sims [4096][4096]
#define OFF_O   ((size_t)58720256)                // f32 O parts
#define OFF_SC  ((size_t)138412032)               // f32 scalars[8]
#define OFF_WX8 (OFF_SC + 2048)
#define OFF_WGB (OFF_SC + 2112)
#define OFF_MR  (OFF_SC + 4096)
#define OFF_MC  (OFF_SC + 4096 + 16384)
#define WS_REQUIRED (OFF_MC + 4096)
#define O_PART  ((size_t)4096 * RN)

DEV u16 f2bf(float f) {
  union { float f; u32 u; } v; v.f = f;
  u32 r = v.u + 0x7FFFu + ((v.u >> 16) & 1u);
  return (u16)(r >> 16);
}
DEV float bf2f(u16 u) {
  union { u32 u; float f; } v; v.u = ((u32)u) << 16;
  return v.f;
}

DEV void glds16(const void* g, void* l) {
  __builtin_amdgcn_global_load_lds(
      (const __attribute__((address_space(1))) void*)g,
      (__attribute__((address_space(3))) void*)l, 16, 0, 0);
}

// ---------------- prep ----------------
__global__ __launch_bounds__(256) void k_prep(const void* wx, const void* wg,
                                              const void* beta, const void* gamma,
                                              const void* coef, float* sc,
                                              char* wx8, u16* wgb) {
  __shared__ int sflag;
  int t = threadIdx.x;
  if (t == 0) {
    u32 u = ((const u32*)wx)[5];
    int f = (u == 0x40400000u) ? 1 : 0;
    sflag = f;
    ((int*)sc)[0] = f;
  }
  __syncthreads();
  int f = sflag;
  auto rd = [&](const void* p, int i) -> float {
    return f ? ((const float*)p)[i] : bf2f(((const u16*)p)[i]);
  };
  if (t == 0) {
    sc[1] = rd(beta, 0); sc[2] = rd(gamma, 0);
    sc[3] = rd(coef, 0); sc[4] = rd(coef, 1); sc[5] = rd(coef, 2);
  }
  for (int i = t; i < 30;  i += 256) wx8[i] = (char)__float2int_rn(rd(wx, i));
  for (int i = t; i < 420; i += 256) wgb[i] = f2bf(rd(wg, i));
}

// ---------------- means ----------------
__global__ __launch_bounds__(64) void k_means_rows(const int* __restrict__ x, float* __restrict__ mr) {
  int i = blockIdx.x, t = threadIdx.x;
  const int* row = x + (size_t)i * MX;
  float s = 0.f, c = 0.f;
  for (int m = t; m < MX; m += 64) { int a = row[m]; s += (float)a; c += (a > 0) ? 1.f : 0.f; }
  for (int off = 32; off >= 1; off >>= 1) { s += __shfl_xor(s, off); c += __shfl_xor(c, off); }
  if (t == 0) mr[i] = s / (c + 1e-5f);
}

__global__ __launch_bounds__(256) void k_means_cols(const int* __restrict__ x, float* __restrict__ mc) {
  int m = blockIdx.x, t = threadIdx.x;
  float s = 0.f, c = 0.f;
  for (int i = t; i < N_USERS; i += 256) { int a = x[(size_t)i * MX + m]; s += (float)a; c += (a > 0) ? 1.f : 0.f; }
  __shared__ float ss[4], cs[4];
  for (int off = 32; off >= 1; off >>= 1) { s += __shfl_xor(s, off); c += __shfl_xor(c, off); }
  int w = t >> 6, lane = t & 63;
  if (lane == 0) { ss[w] = s; cs[w] = c; }
  __syncthreads();
  if (t == 0) {
    s = ss[0] + ss[1] + ss[2] + ss[3];
    c = cs[0] + cs[1] + cs[2] + cs[3];
    mc[m] = s / (c + 1e-5f);
  }
}

__global__ __launch_bounds__(256) void k_scalars(const float* __restrict__ mr, const float* __restrict__ mc, float* sc) {
  int t = threadIdx.x;
  float s1 = 0.f, s2 = 0.f;
  for (int i = t; i < N_USERS; i += 256) s1 += mr[i];
  for (int i = t; i < MX; i += 256) s2 += mc[i];
  __shared__ float a1[4], a2[4];
  for (int off = 32; off >= 1; off >>= 1) { s1 += __shfl_xor(s1, off); s2 += __shfl_xor(s2, off); }
  int w = t >> 6, lane = t & 63;
  if (lane == 0) { a1[w] = s1; a2[w] = s2; }
  __syncthreads();
  if (t == 0) {
    sc[6] = (a1[0] + a1[1] + a1[2] + a1[3]) / (float)N_USERS;
    sc[7] = (a2[0] + a2[1] + a2[2] + a2[3]) / (float)MX;
  }
}

// ---------------- build operands ----------------
__global__ __launch_bounds__(256) void k_buildAB(const int* __restrict__ xi, const int* __restrict__ gi,
                                                 const char* __restrict__ wx8, const u16* __restrict__ wgb,
                                                 char* __restrict__ A8, char* __restrict__ B8,
                                                 u16* __restrict__ A16, u16* __restrict__ B16) {
  int i = blockIdx.x, t = threadIdx.x;
  char* a8 = A8 + (size_t)i * KR8;
  char* b8 = B8 + (size_t)i * KR8;
  u16* a16 = A16 + (size_t)i * KG16;
  u16* b16 = B16 + (size_t)i * KG16;
  const int* xr = xi + (size_t)i * MX;
  const int* gr = gi + (size_t)i * MG;
  for (int m = t; m < MX; m += 256) {
    int a = xr[m];
    int base = m * 5;
#pragma unroll
    for (int d = 0; d < 5; ++d) {
      a8[base + d] = wx8[a * 5 + d];
      b8[base + d] = (a == d + 1) ? (char)1 : (char)0;
    }
  }
  for (int e = 2500 + t; e < KR8; e += 256) { a8[e] = 0; b8[e] = 0; }
  for (int m = t; m < MG; m += 256) {
    int g = gr[m];
    int base = m * 20;
#pragma unroll
    for (int d = 0; d < 20; ++d) {
      a16[base + d] = wgb[g * 20 + d];
      b16[base + d] = (g == d + 1) ? (u16)0x3F80 : (u16)0;
    }
  }
  for (int e = 1000 + t; e < KG16; e += 256) { a16[e] = 0; b16[e] = 0; }
}

// ---------------- mixed i8+bf16 256x256 GEMM, 16 waves, ring-4, loose pipeline ----------------
// C = Ai8 * Bi8^T (i32, exact) + Abf * Bbf^T (f32).  Row strides in BYTES.
// 16 waves (4 M x 4 N, wave tile 64x64) -> 4 waves/SIMD so wave-TLP hides
// LDS/DMA latency. One barrier per K-step; counted vmcnt; compiler schedules
// inside the step. K-step = 64 B per row (32 bf16 / 64 i8).
__global__ __launch_bounds__(1024, 4) void k_gemm_mix(
    const char* __restrict__ A8, const char* __restrict__ B8,
    const char* __restrict__ A16, const char* __restrict__ B16,
    float* __restrict__ Cg, int N, int nt1, int ntT,
    int lda8, int ldb8, int lda16, int ldb16,
    int kz16, unsigned long long czStride)
{
  extern __shared__ __align__(16) char ldsc[];   // ring[4] x {A 16KB, B 16KB} = 128 KiB
  int t = threadIdx.x, lane = t & 63, w = t >> 6;

  // XCD-aware bijective swizzle (nwg % 8 == 0 for all our grids)
  int nwg = gridDim.x * gridDim.y;
  int o = blockIdx.y * gridDim.x + blockIdx.x;
  int swz = (o & 7) * (nwg >> 3) + (o >> 3);
  int bn = swz % gridDim.x, bm = swz / gridDim.x;

  const char* pA8b  = A8  + (size_t)bm * 256 * lda8;
  const char* pB8b  = B8  + (size_t)bn * 256 * ldb8;
  const char* pA16b = A16 + (size_t)bm * 256 * lda16 + (size_t)blockIdx.z * kz16;
  const char* pB16b = B16 + (size_t)bn * 256 * ldb16 + (size_t)blockIdx.z * kz16;
  float* C = Cg + (size_t)blockIdx.z * czStride;

  int wm = w >> 2, wn = w & 3;                 // 4M x 4N waves; wave tile 64x64

  // fragment LDS byte offsets (swizzle: slot ^= (row&3)^((row>>2)&1))
  int aoffs[2][2], boffs[2][2];
#pragma unroll
  for (int m = 0; m < 2; ++m)
#pragma unroll
    for (int ks = 0; ks < 2; ++ks) {
      int row = wm * 64 + m * 32 + (lane & 31);
      int slot = ((ks << 1) | (lane >> 5)) ^ ((row & 3) ^ ((row >> 2) & 1));
      aoffs[m][ks] = row * 64 + slot * 16;
    }
#pragma unroll
  for (int n = 0; n < 2; ++n)
#pragma unroll
    for (int ks = 0; ks < 2; ++ks) {
      int col = wn * 64 + n * 32 + (lane & 31);
      int slot = ((ks << 1) | (lane >> 5)) ^ ((col & 3) ^ ((col >> 2) & 1));
      boffs[n][ks] = col * 64 + slot * 16;
    }

  // staging: waves 0-7 stage A, 8-15 stage B; 2 glds16 each (1KB per call);
  // global source pre-swizzled so linear LDS dest ends up swizzled.
  const char* src8[2]; const char* src16[2]; int dsto[2];
  {
    const char* b8p  = (w < 8) ? pA8b  : pB8b;
    const char* b16p = (w < 8) ? pA16b : pB16b;
    int ld8  = (w < 8) ? lda8  : ldb8;
    int ld16 = (w < 8) ? lda16 : ldb16;
#pragma unroll
    for (int c = 0; c < 2; ++c) {
      int q = (w & 7) * 2 + c;
      int row = q * 16 + (lane >> 2);
      int slot = (lane & 3) ^ ((row & 3) ^ ((row >> 2) & 1));
      dsto[c] = ((w < 8) ? 0 : 16384) + q * 1024;
      src8[c]  = b8p  + (size_t)row * ld8  + slot * 16;
      src16[c] = b16p + (size_t)row * ld16 + slot * 16;
    }
  }

  auto stage = [&](int s) {
    if (s >= ntT) return;
    char* dst = ldsc + ((size_t)(s & 3) << 15);
    if (s < nt1) {
      size_t ko = (size_t)s * 64;
#pragma unroll
      for (int c = 0; c < 2; ++c) glds16(src8[c] + ko, dst + dsto[c]);
    } else {
      size_t ko = (size_t)(s - nt1) * 64;
#pragma unroll
      for (int c = 0; c < 2; ++c) glds16(src16[c] + ko, dst + dsto[c]);
    }
  };

#define STEP_TAIL(s)                                                        \
  do {                                                                      \
    int r_ = ntT - 1 - (s);                                                 \
    if (r_ >= 3)      asm volatile("s_waitcnt vmcnt(4)" ::: "memory");      \
    else if (r_ == 2) asm volatile("s_waitcnt vmcnt(2)" ::: "memory");      \
    else if (r_ == 1) asm volatile("s_waitcnt vmcnt(0)" ::: "memory");      \
    if (r_ >= 1) {                                                          \
      __builtin_amdgcn_s_barrier();                                         \
      __builtin_amdgcn_sched_barrier(0);                                    \
    }                                                                       \
  } while (0)

  // prologue: stage tiles 0..2, wait tile 0
  stage(0); stage(1); stage(2);
  asm volatile("s_waitcnt vmcnt(4)" ::: "memory");
  __builtin_amdgcn_s_barrier();
  __builtin_amdgcn_sched_barrier(0);

  i32x16 acc[2][2] = {};
  f32x16 (&accF)[2][2] = reinterpret_cast<f32x16(&)[2][2]>(acc);

  // ---- loop 1: i8 (rating), exact i32 accumulate ----
  for (int s = 0; s < nt1; ++s) {
    const char* At = ldsc + ((size_t)(s & 3) << 15);
    const char* Bt = At + 16384;
    stage(s + 3);
    i32x4 av[2][2], bv[2][2];
#pragma unroll
    for (int m = 0; m < 2; ++m)
#pragma unroll
      for (int ks = 0; ks < 2; ++ks) av[m][ks] = *(const i32x4*)(At + aoffs[m][ks]);
#pragma unroll
    for (int n = 0; n < 2; ++n)
#pragma unroll
      for (int ks = 0; ks < 2; ++ks) bv[n][ks] = *(const i32x4*)(Bt + boffs[n][ks]);
    __builtin_amdgcn_s_setprio(1);
#pragma unroll
    for (int ks = 0; ks < 2; ++ks)
#pragma unroll
      for (int m = 0; m < 2; ++m)
#pragma unroll
        for (int n = 0; n < 2; ++n)
          acc[m][n] = __builtin_amdgcn_mfma_i32_32x32x32_i8(av[m][ks], bv[n][ks], acc[m][n], 0, 0, 0);
    __builtin_amdgcn_s_setprio(0);
    STEP_TAIL(s);
  }

  // convert i32 -> f32 in place
#pragma unroll
  for (int m = 0; m < 2; ++m)
#pragma unroll
    for (int n = 0; n < 2; ++n)
#pragma unroll
      for (int e = 0; e < 16; ++e) {
        int v = acc[m][n][e];
        accF[m][n][e] = (float)v;
      }

  // ---- loop 2: bf16 (genre / GEMM2) ----
  for (int s = nt1; s < ntT; ++s) {
    const char* At = ldsc + ((size_t)(s & 3) << 15);
    const char* Bt = At + 16384;
    stage(s + 3);
    bf16x8 av[2][2], bv[2][2];
#pragma unroll
    for (int m = 0; m < 2; ++m)
#pragma unroll
      for (int ks = 0; ks < 2; ++ks) av[m][ks] = *(const bf16x8*)(At + aoffs[m][ks]);
#pragma unroll
    for (int n = 0; n < 2; ++n)
#pragma unroll
      for (int ks = 0; ks < 2; ++ks) bv[n][ks] = *(const bf16x8*)(Bt + boffs[n][ks]);
    __builtin_amdgcn_s_setprio(1);
#pragma unroll
    for (int ks = 0; ks < 2; ++ks)
#pragma unroll
      for (int m = 0; m < 2; ++m)
#pragma unroll
        for (int n = 0; n < 2; ++n)
          accF[m][n] = __builtin_amdgcn_mfma_f32_32x32x16_bf16(av[m][ks], bv[n][ks], accF[m][n], 0, 0, 0);
    __builtin_amdgcn_s_setprio(0);
    STEP_TAIL(s);
  }
#undef STEP_TAIL

  // C write: 32x32 C/D layout: col = lane&31, row = (r&3) + 8*(r>>2) + 4*(lane>>5)
  int colb = bn * 256 + wn * 64 + (lane & 31);
  int rowb = bm * 256 + wm * 64 + ((lane >> 5) << 2);
#pragma unroll
  for (int m = 0; m < 2; ++m)
#pragma unroll
    for (int n = 0; n < 2; ++n) {
      float* Cp = C + (size_t)(rowb + m * 32) * N + colb + n * 32;
#pragma unroll
      for (int r = 0; r < 16; ++r) {
        int rr = (r & 3) + 8 * (r >> 2);
        Cp[(size_t)rr * N] = accF[m][n][r];
      }
    }
}

// ---------------- softmax ----------------
__global__ __launch_bounds__(256) void k_softmax(const float* __restrict__ S, u16* __restrict__ P,
                                                 const float* __restrict__ sc) {
  int i = blockIdx.x, t = threadIdx.x;
  const float* row = S + (size_t)i * N_USERS;
  float v[16];
#pragma unroll
  for (int c = 0; c < 4; ++c) {
    float4 f = *(const float4*)&row[(c * 256 + t) * 4];
    v[c * 4 + 0] = f.x; v[c * 4 + 1] = f.y; v[c * 4 + 2] = f.z; v[c * 4 + 3] = f.w;
  }
#pragma unroll
  for (int c = 0; c < 4; ++c) {
    int j0 = (c * 256 + t) * 4;
#pragma unroll
    for (int q = 0; q < 4; ++q) if (j0 + q == i) v[c * 4 + q] = 0.f;
  }
  float mx = -1e30f;
#pragma unroll
  for (int e = 0; e < 16; ++e) mx = fmaxf(mx, v[e]);
  __shared__ float red[8];
  for (int off = 32; off >= 1; off >>= 1) mx = fmaxf(mx, __shfl_xor(mx, off));
  int w = t >> 6, lane = t & 63;
  if (lane == 0) red[w] = mx;
  __syncthreads();
  mx = fmaxf(fmaxf(red[0], red[1]), fmaxf(red[2], red[3]));

  float invT = 1.f / (powf(mx + 0.001f, sc[2]) * sc[1]);
  float s = 0.f;
#pragma unroll
  for (int e = 0; e < 16; ++e) { v[e] = expf((v[e] - mx) * invT); s += v[e]; }
  for (int off = 32; off >= 1; off >>= 1) s += __shfl_xor(s, off);
  if (lane == 0) red[4 + w] = s;
  __syncthreads();
  s = red[4] + red[5] + red[6] + red[7];
  float rs = 1.f / s;

  u16* prow = P + (size_t)i * N_USERS;
#pragma unroll
  for (int c = 0; c < 4; ++c) {
    int j0 = (c * 256 + t) * 4;
    union { u16 q[4]; uint2 u; } pk;
#pragma unroll
    for (int q = 0; q < 4; ++q) pk.q[q] = f2bf(v[c * 4 + q] * rs);
    *(uint2*)&prow[j0] = pk.u;
  }
}

// ---------------- build RHS^T ----------------
__global__ __launch_bounds__(256) void k_buildR(const int* __restrict__ xi, const float* __restrict__ mr,
                                                u16* __restrict__ R) {
  int k = blockIdx.x * 256 + threadIdx.x;
  int n = blockIdx.y;
  u16 v;
  if (n < 500)       { int a = xi[(size_t)k * MX + n];          v = f2bf((float)a); }
  else if (n < 1000) { int a = xi[(size_t)k * MX + (n - 500)];  v = (a > 0) ? (u16)0x3F80 : (u16)0; }
  else if (n < 1500) { int a = xi[(size_t)k * MX + (n - 1000)]; v = (a > 0) ? f2bf(mr[k]) : (u16)0; }
  else v = 0;
  R[(size_t)n * N_USERS + k] = v;
}

// ---------------- final ----------------
__global__ __launch_bounds__(256) void k_final(const float* __restrict__ O, const float* __restrict__ mr,
                                               const float* __restrict__ mc, const float* __restrict__ sc,
                                               void* __restrict__ out) {
  int m = blockIdx.x * 256 + threadIdx.x;
  int i = blockIdx.y;
  if (m >= MX) return;
  const float* o0 = O + (size_t)i * RN;
  const float* o1 = o0 + O_PART;
  float mult  = o0[m] + o1[m];
  float scale = o0[500 + m] + o1[500 + m] + 1e-4f;
  float mrs   = (o0[1000 + m] + o1[1000 + m]) / scale;
  float res   = mult / scale;
  float c0 = sc[3], c1 = sc[4], c2 = sc[5], mrm = sc[6], mcm = sc[7];
  float add = (mr[i] - mrs) * c0 + (mc[m] - mcm) * c1 + (mr[i] - mrm) * c2;
  float r = res + add;
  r = fminf(fmaxf(r, 1.f), 5.f);
  int f32mode = ((const int*)sc)[0];
  if (f32mode) ((float*)out)[(size_t)i * MX + m] = r;
  else         ((u16*)out)[(size_t)i * MX + m] = f2bf(r);
}

extern "C" void kernel_launch(void* const* d_in, const int* in_sizes, int n_in,
                              void* d_out, int out_size, void* d_ws, size_t ws_size,
                              hipStream_t stream) {
  if (ws_size < WS_REQUIRED) return;
  const int* xi = (const int*)d_in[0];
  const int* gi = (const int*)d_in[1];
  char* ws = (char*)d_ws;
  char*  A8  = ws + OFF_A8;
  char*  B8  = ws + OFF_B8;
  u16*   A16 = (u16*)(ws + OFF_A16);
  u16*   B16 = (u16*)(ws + OFF_B16);
  u16*   P   = (u16*)(ws + OFF_P);
  float* S   = (float*)(ws + OFF_S);
  float* O   = (float*)(ws + OFF_O);
  u16*   R   = (u16*)(ws + OFF_R);
  float* sc  = (float*)(ws + OFF_SC);
  char*  wx8 = ws + OFF_WX8;
  u16*   wgb = (u16*)(ws + OFF_WGB);
  float* mr  = (float*)(ws + OFF_MR);
  float* mc  = (float*)(ws + OFF_MC);

  (void)hipFuncSetAttribute((const void*)k_gemm_mix,
                            hipFuncAttributeMaxDynamicSharedMemorySize, 131072);

  k_prep<<<1, 256, 0, stream>>>(d_in[2], d_in[4], d_in[6], d_in[7], d_in[8], sc, wx8, wgb);
  k_means_rows<<<N_USERS, 64, 0, stream>>>(xi, mr);
  k_means_cols<<<MX, 256, 0, stream>>>(xi, mc);
  k_scalars<<<1, 256, 0, stream>>>(mr, mc, sc);
  k_buildAB<<<N_USERS, 256, 0, stream>>>(xi, gi, wx8, wgb, A8, B8, A16, B16);
  // GEMM1: sims = A8*B8^T (i8, K=2560) + A16*B16^T (bf16, K=1024)
  k_gemm_mix<<<dim3(16, 16, 1), 1024, 131072, stream>>>(
      A8, B8, (const char*)A16, (const char*)B16, S, N_USERS,
      KR8 / 64, KR8 / 64 + KG16 / 32, KR8, KR8, KG16 * 2, KG16 * 2, 0, 0ull);
  k_softmax<<<N_USERS, 256, 0, stream>>>(S, P, sc);
  k_buildR<<<dim3(16, RN), 256, 0, stream>>>(xi, mr, R);
  // GEMM2: O = P * R^T  [4096 x 1536 x 4096], bf16 only, split-K=2
  k_gemm_mix<<<dim3(RN / 256, 16, 2), 1024, 131072, stream>>>(
      (const char*)P, (const char*)R, (const char*)P, (const char*)R, O, RN,
      0, (N_USERS / 2) / 32, 0, 0, N_USERS * 2, N_USERS * 2,
      (N_USERS / 2) * 2, (unsigned long long)O_PART);
  k_final<<<dim3(2, N_USERS), 256, 0, stream>>>(O, mr, mc, sc, d_out);
}